// Round 18
// baseline (68.199 us; speedup 1.0000x reference)
//
#include <hip/hip_runtime.h>
#include <hip/hip_cooperative_groups.h>
#include <math.h>

// GaussianMixtureLoss: loss = CONST - mean_{b,n}( ln sum_m exp(p·g - |g|²/2) - |p|²/2 )
// B=4, N=4096, M=4096, D=3, SIGMA=1.
// R18: SINGLE cooperative dispatch. gm_main body = R17 (16.76us base);
// after bsum store -> grid.sync() -> block 0 reduces 512 partials, writes
// out[0]. Deletes the gm_reduce dispatch + inter-dispatch gap (~6.8us
// K2+OH measured in R7). No ws init needed (R15 lesson: in-graph memset
// costs ~39us). 512 blocks x 256thr, 33KB LDS -> 4 blocks/CU capacity,
// co-residency (needs 2/CU) trivially satisfied.
#define BATCH 4
#define NPTS 4096
#define NMIX 4096
#define THREADS 256
#define PPB 32                // points per block
#define PTS 8                 // points per thread
#define MSTAGE 2048           // mixtures staged per pass (1024 pairs, 32 KB)
#define PASSES (NMIX / MSTAGE)
#define JITER 16              // 1024 pairs / 64 mixture-lanes per pass
#define NBLOCKS ((BATCH * NPTS) / PPB)  // 512

#define LN2 0.6931471805599453f
#define CONST_TERM 0.9189385332046727f  // 0.5*log(2*pi)
#define INV_COUNT (1.0f / (float)(BATCH * NPTS))
// Schraudolph folded: K = 2^23*log2(e); BIAS = 2^23*(127-0.0563)
#define SEXP_K    12102203.0f
#define SEXP_BIAS 1.06488094e9f

namespace cg = cooperative_groups;

typedef float v2f __attribute__((ext_vector_type(2)));

__device__ __forceinline__ float fast_log2(float x) {
#if __has_builtin(__builtin_amdgcn_logf)
  return __builtin_amdgcn_logf(x);
#else
  return log2f(x);
#endif
}

__device__ __forceinline__ v2f pk_fma(v2f a, v2f b, v2f c) {
  v2f d;
  asm("v_pk_fma_f32 %0, %1, %2, %3" : "=v"(d) : "v"(a), "v"(b), "v"(c));
  return d;
}

__global__ __launch_bounds__(THREADS) void gm_main(
    const float* __restrict__ pred, const float* __restrict__ gt,
    float* __restrict__ bsum, float* __restrict__ out) {
  __shared__ float4 gsh[MSTAGE];   // 32 KB (1024 pairs x 2 float4)
  __shared__ float wpart[4][32];   // [wave][col]
  float* comb = (float*)gsh;       // aliased tail buffer [64][33]

  const int t = threadIdx.x;
  const int b = blockIdx.x >> 7;             // 128 blocks per batch
  const int n0 = (blockIdx.x & 127) * PPB;
  const int pl = t & 3;                      // point quarter (8 pts each)
  const int ml = t >> 2;                     // mixture-pair lane 0..63

  // 8 scalar points, hoisted as broadcast pairs for pk_fma
  v2f px2[PTS], py2[PTS], pz2[PTS], acc[PTS];
#pragma unroll
  for (int k = 0; k < PTS; ++k) {
    const float* p = pred + ((size_t)(b * NPTS + n0 + pl * PTS + k)) * 3;
    px2[k] = (v2f){p[0], p[0]};
    py2[k] = (v2f){p[1], p[1]};
    pz2[k] = (v2f){p[2], p[2]};
    acc[k] = (v2f){0.f, 0.f};
  }

  for (int q = 0; q < PASSES; ++q) {
    __syncthreads();  // prior-pass readers done
#pragma unroll
    for (int i = 0; i < 4; ++i) {
      int s = t + i * THREADS;  // pair index 0..1023
      const float2* g = (const float2*)(gt +
          ((size_t)(b * NMIX + q * MSTAGE + 2 * s)) * 3);
      float2 g01 = g[0], g23 = g[1], g45 = g[2];
      // mixture 2s: (g01.x, g01.y, g23.x); 2s+1: (g23.y, g45.x, g45.y)
      float n20 = fmaf(g01.x, g01.x, fmaf(g01.y, g01.y, g23.x * g23.x));
      float n21 = fmaf(g23.y, g23.y, fmaf(g45.x, g45.x, g45.y * g45.y));
      gsh[2 * s]     = make_float4(SEXP_K * g01.x, SEXP_K * g23.y,
                                   SEXP_K * g01.y, SEXP_K * g45.x);
      gsh[2 * s + 1] = make_float4(SEXP_K * g23.x, SEXP_K * g45.y,
                                   fmaf(n20, -0.5f * SEXP_K, SEXP_BIAS),
                                   fmaf(n21, -0.5f * SEXP_K, SEXP_BIAS));
    }
    __syncthreads();

#pragma unroll 2
    for (int j = 0; j < JITER; ++j) {
      int s = ml + 64 * j;
      float4 a = gsh[2 * s];      // {Kgx0,Kgx1,Kgy0,Kgy1}
      float4 c4 = gsh[2 * s + 1]; // {Kgz0,Kgz1,w0,w1}
      v2f gx2 = (v2f){a.x, a.y}, gy2 = (v2f){a.z, a.w};
      v2f gz2 = (v2f){c4.x, c4.y}, w2 = (v2f){c4.z, c4.w};
#pragma unroll
      for (int k = 0; k < PTS; ++k) {
        v2f d = pk_fma(pz2[k], gz2, w2);
        d = pk_fma(py2[k], gy2, d);
        d = pk_fma(px2[k], gx2, d);
        v2f e;                                    // Schraudolph exp, packed
        e.x = __builtin_bit_cast(float, (int)d.x);
        e.y = __builtin_bit_cast(float, (int)d.y);
        acc[k] += e;
      }
    }
  }

  __syncthreads();  // all gsh reads done before aliasing as comb

  // comb[ml][pl*8+k]: both mixture halves pre-summed; [64][33] padded
#pragma unroll
  for (int k = 0; k < PTS; ++k)
    comb[ml * (PPB + 1) + pl * PTS + k] = acc[k].x + acc[k].y;
  __syncthreads();

  {
    const int col = t & 31, grp = t >> 5;  // 8 groups x 8 rows
    float s = 0.f;
#pragma unroll
    for (int r = 0; r < 8; ++r) s += comb[(grp * 8 + r) * (PPB + 1) + col];
    s += __shfl_down(s, 32, 64);
    if ((t & 63) < 32) wpart[t >> 6][col] = s;
  }
  __syncthreads();

  if (t < 32) {
    float s = (wpart[0][t] + wpart[1][t]) + (wpart[2][t] + wpart[3][t]);
    const float* p = pred + ((size_t)(b * NPTS + n0 + t)) * 3;
    float hp2 = 0.5f * (p[0] * p[0] + p[1] * p[1] + p[2] * p[2]);
    float ll = (LN2 * fast_log2(s) - hp2) * INV_COUNT;
#pragma unroll
    for (int off = 16; off > 0; off >>= 1) ll += __shfl_down(ll, off, 32);
    if (t == 0) bsum[blockIdx.x] = ll;
  }

  // ---- fused final reduce: grid-wide sync, block 0 finishes ----
  cg::this_grid().sync();
  if (blockIdx.x == 0) {
    float v = bsum[t] + bsum[t + 256];  // 512 entries
    for (int off = 32; off > 0; off >>= 1) v += __shfl_down(v, off, 64);
    if ((t & 63) == 0) wpart[0][t >> 6] = v;
    __syncthreads();
    if (t == 0)
      out[0] = CONST_TERM - ((wpart[0][0] + wpart[0][1]) +
                             (wpart[0][2] + wpart[0][3]));
  }
}

extern "C" void kernel_launch(void* const* d_in, const int* in_sizes, int n_in,
                              void* d_out, int out_size, void* d_ws, size_t ws_size,
                              hipStream_t stream) {
  const float* pred = (const float*)d_in[0];
  const float* gt   = (const float*)d_in[1];
  float* out = (float*)d_out;
  float* bsum = (float*)d_ws;  // 512 floats, fully overwritten every call

  void* args[] = {(void*)&pred, (void*)&gt, (void*)&bsum, (void*)&out};
  hipLaunchCooperativeKernel((const void*)gm_main, dim3(NBLOCKS),
                             dim3(THREADS), args, 0, stream);
}

// Round 19
// 15.971 us; speedup vs baseline: 4.2701x; 4.2701x over previous
//
#include <hip/hip_runtime.h>
#include <math.h>

// GaussianMixtureLoss: loss = CONST - mean_{b,n}( ln sum_m exp(p·g - |g|²/2) - |p|²/2 )
// B=4, N=4096, M=4096, D=3, SIGMA=1.
// R19: R17 + SINGLE-PASS staging (MSTAGE=4096, 64KB LDS, still 2 blocks/CU)
//  - no prior readers before first stage -> pre-stage barrier deleted;
//    barrier count 6 -> 4. All 24 staging loads issue in one burst.
//  - j-loop unroll-8: ds_read addresses become base + immediate offsets.
//  - inner math / tail / gm_reduce byte-identical to R17 (16.76us base).
// (R18 lesson: grid.sync costs ~35us; R15: in-graph memset ~39us. 2-dispatch
//  no-init structure is the floor for launch organization.)
#define BATCH 4
#define NPTS 4096
#define NMIX 4096
#define THREADS 256
#define PPB 32                // points per block
#define PTS 8                 // points per thread
#define NPAIR (NMIX / 2)      // 2048 mixture pairs, staged once (64 KB)
#define JITER (NPAIR / 64)    // 32 j-iters (ml lanes = 64)
#define NBLOCKS ((BATCH * NPTS) / PPB)  // 512

#define LN2 0.6931471805599453f
#define CONST_TERM 0.9189385332046727f  // 0.5*log(2*pi)
#define INV_COUNT (1.0f / (float)(BATCH * NPTS))
// Schraudolph folded: K = 2^23*log2(e); BIAS = 2^23*(127-0.0563)
#define SEXP_K    12102203.0f
#define SEXP_BIAS 1.06488094e9f

typedef float v2f __attribute__((ext_vector_type(2)));

__device__ __forceinline__ float fast_log2(float x) {
#if __has_builtin(__builtin_amdgcn_logf)
  return __builtin_amdgcn_logf(x);
#else
  return log2f(x);
#endif
}

__device__ __forceinline__ v2f pk_fma(v2f a, v2f b, v2f c) {
  v2f d;
  asm("v_pk_fma_f32 %0, %1, %2, %3" : "=v"(d) : "v"(a), "v"(b), "v"(c));
  return d;
}

__global__ __launch_bounds__(THREADS) void gm_main(
    const float* __restrict__ pred, const float* __restrict__ gt,
    float* __restrict__ bsum) {
  __shared__ float4 gsh[2 * NPAIR];  // 64 KB (2048 pairs x 2 float4)
  __shared__ float wpart[4][32];     // [wave][col]
  float* comb = (float*)gsh;         // aliased tail buffer [64][33]

  const int t = threadIdx.x;
  const int b = blockIdx.x >> 7;             // 128 blocks per batch
  const int n0 = (blockIdx.x & 127) * PPB;
  const int pl = t & 3;                      // point quarter (8 pts each)
  const int ml = t >> 2;                     // mixture-pair lane 0..63

  // 8 scalar points, hoisted as broadcast pairs for pk_fma
  v2f px2[PTS], py2[PTS], pz2[PTS], acc[PTS];
#pragma unroll
  for (int k = 0; k < PTS; ++k) {
    const float* p = pred + ((size_t)(b * NPTS + n0 + pl * PTS + k)) * 3;
    px2[k] = (v2f){p[0], p[0]};
    py2[k] = (v2f){p[1], p[1]};
    pz2[k] = (v2f){p[2], p[2]};
    acc[k] = (v2f){0.f, 0.f};
  }

  // single-pass stage: all 2048 pairs, no pre-barrier (no prior readers)
#pragma unroll
  for (int i = 0; i < NPAIR / THREADS; ++i) {
    int s = t + i * THREADS;  // pair index 0..2047
    const float2* g = (const float2*)(gt + ((size_t)(b * NMIX + 2 * s)) * 3);
    float2 g01 = g[0], g23 = g[1], g45 = g[2];
    // mixture 2s: (g01.x, g01.y, g23.x); 2s+1: (g23.y, g45.x, g45.y)
    float n20 = fmaf(g01.x, g01.x, fmaf(g01.y, g01.y, g23.x * g23.x));
    float n21 = fmaf(g23.y, g23.y, fmaf(g45.x, g45.x, g45.y * g45.y));
    gsh[2 * s]     = make_float4(SEXP_K * g01.x, SEXP_K * g23.y,
                                 SEXP_K * g01.y, SEXP_K * g45.x);
    gsh[2 * s + 1] = make_float4(SEXP_K * g23.x, SEXP_K * g45.y,
                                 fmaf(n20, -0.5f * SEXP_K, SEXP_BIAS),
                                 fmaf(n21, -0.5f * SEXP_K, SEXP_BIAS));
  }
  __syncthreads();

  {
    const float4* gbase = gsh + 2 * ml;  // per-j offsets are immediates
#pragma unroll 8
    for (int j = 0; j < JITER; ++j) {
      float4 a = gbase[128 * j];      // {Kgx0,Kgx1,Kgy0,Kgy1}
      float4 c4 = gbase[128 * j + 1]; // {Kgz0,Kgz1,w0,w1}
      v2f gx2 = (v2f){a.x, a.y}, gy2 = (v2f){a.z, a.w};
      v2f gz2 = (v2f){c4.x, c4.y}, w2 = (v2f){c4.z, c4.w};
#pragma unroll
      for (int k = 0; k < PTS; ++k) {
        v2f d = pk_fma(pz2[k], gz2, w2);
        d = pk_fma(py2[k], gy2, d);
        d = pk_fma(px2[k], gx2, d);
        v2f e;                                    // Schraudolph exp, packed
        e.x = __builtin_bit_cast(float, (int)d.x);
        e.y = __builtin_bit_cast(float, (int)d.y);
        acc[k] += e;
      }
    }
  }

  __syncthreads();  // all gsh reads done before aliasing as comb

  // comb[ml][pl*8+k]: both mixture halves pre-summed; [64][33] padded
#pragma unroll
  for (int k = 0; k < PTS; ++k)
    comb[ml * (PPB + 1) + pl * PTS + k] = acc[k].x + acc[k].y;
  __syncthreads();

  {
    const int col = t & 31, grp = t >> 5;  // 8 groups x 8 rows
    float s = 0.f;
#pragma unroll
    for (int r = 0; r < 8; ++r) s += comb[(grp * 8 + r) * (PPB + 1) + col];
    s += __shfl_down(s, 32, 64);
    if ((t & 63) < 32) wpart[t >> 6][col] = s;
  }
  __syncthreads();

  if (t < 32) {
    float s = (wpart[0][t] + wpart[1][t]) + (wpart[2][t] + wpart[3][t]);
    const float* p = pred + ((size_t)(b * NPTS + n0 + t)) * 3;
    float hp2 = 0.5f * (p[0] * p[0] + p[1] * p[1] + p[2] * p[2]);
    float ll = (LN2 * fast_log2(s) - hp2) * INV_COUNT;
#pragma unroll
    for (int off = 16; off > 0; off >>= 1) ll += __shfl_down(ll, off, 32);
    if (t == 0) bsum[blockIdx.x] = ll;
  }
}

__global__ __launch_bounds__(THREADS) void gm_reduce(
    const float* __restrict__ bsum, float* __restrict__ out) {
  const int t = threadIdx.x;
  float v = bsum[t] + bsum[t + 256];  // 512 entries
  for (int off = 32; off > 0; off >>= 1) v += __shfl_down(v, off, 64);
  __shared__ float w[4];
  if ((t & 63) == 0) w[t >> 6] = v;
  __syncthreads();
  if (t == 0) out[0] = CONST_TERM - ((w[0] + w[1]) + (w[2] + w[3]));
}

extern "C" void kernel_launch(void* const* d_in, const int* in_sizes, int n_in,
                              void* d_out, int out_size, void* d_ws, size_t ws_size,
                              hipStream_t stream) {
  const float* pred = (const float*)d_in[0];
  const float* gt   = (const float*)d_in[1];
  float* out = (float*)d_out;
  float* bsum = (float*)d_ws;  // 512 floats, fully overwritten every call

  gm_main<<<NBLOCKS, THREADS, 0, stream>>>(pred, gt, bsum);
  gm_reduce<<<1, THREADS, 0, stream>>>(bsum, out);
}